// Round 6
// baseline (8294.845 us; speedup 1.0000x reference)
//
#include <hip/hip_runtime.h>
#include <cstdint>
#include <cstddef>

typedef __attribute__((ext_vector_type(8))) short s8v;          // 8 bf16
typedef __attribute__((ext_vector_type(4))) float f4v;
typedef __attribute__((ext_vector_type(4))) unsigned int u4v;

#define DEVFN __device__ __forceinline__

DEVFN unsigned short f2bf(float f) {
    unsigned int u = __builtin_bit_cast(unsigned int, f);
    return (unsigned short)((u + 0x7FFFu + ((u >> 16) & 1u)) >> 16);
}
DEVFN float bf2f(unsigned short h) {
    unsigned int u = ((unsigned int)h) << 16;
    return __builtin_bit_cast(float, u);
}
DEVFN float sigm(float x) { return 1.0f / (1.0f + __expf(-x)); }
DEVFN float tanh_fast(float x) { float e = __expf(2.0f * x); return 1.0f - 2.0f / (e + 1.0f); }

DEVFN u4v pack8(const unsigned short o[8]) {
    u4v v;
    v[0] = (unsigned)o[0] | ((unsigned)o[1] << 16);
    v[1] = (unsigned)o[2] | ((unsigned)o[3] << 16);
    v[2] = (unsigned)o[4] | ((unsigned)o[5] << 16);
    v[3] = (unsigned)o[6] | ((unsigned)o[7] << 16);
    return v;
}

// device-scope (LLC) write-through store — visible across XCDs, no fence.
DEVFN void store_wt(unsigned int* p, unsigned int v) {
    asm volatile("global_store_dword %0, %1, off sc0 sc1"
                 :: "v"(p), "v"(v) : "memory");
}
// LLC-direct dword read (bypasses stale L1/L2).
DEVFN unsigned poll_load(const unsigned int* p) {
    unsigned v;
    asm volatile("global_load_dword %0, %1, off sc0 sc1\n\t"
                 "s_waitcnt vmcnt(0)"
                 : "=v"(v) : "v"(p) : "memory");
    return v;
}
// merged poll+gather: 16x dwordx4 tagged-h loads + 1 progress dword, LLC-direct.
DEVFN void gather_tagged(const void* b0, const void* b1, const void* b2,
                         const void* b3, const void* pp,
                         u4v& g0, u4v& g1, u4v& g2, u4v& g3,
                         u4v& g4, u4v& g5, u4v& g6, u4v& g7,
                         u4v& g8, u4v& g9, u4v& g10, u4v& g11,
                         u4v& g12, u4v& g13, u4v& g14, u4v& g15,
                         unsigned& pv) {
    asm volatile(
        "global_load_dwordx4 %0, %17, off sc0 sc1\n\t"
        "global_load_dwordx4 %1, %17, off offset:16 sc0 sc1\n\t"
        "global_load_dwordx4 %2, %17, off offset:2048 sc0 sc1\n\t"
        "global_load_dwordx4 %3, %17, off offset:2064 sc0 sc1\n\t"
        "global_load_dwordx4 %4, %18, off sc0 sc1\n\t"
        "global_load_dwordx4 %5, %18, off offset:16 sc0 sc1\n\t"
        "global_load_dwordx4 %6, %18, off offset:2048 sc0 sc1\n\t"
        "global_load_dwordx4 %7, %18, off offset:2064 sc0 sc1\n\t"
        "global_load_dwordx4 %8, %19, off sc0 sc1\n\t"
        "global_load_dwordx4 %9, %19, off offset:16 sc0 sc1\n\t"
        "global_load_dwordx4 %10, %19, off offset:2048 sc0 sc1\n\t"
        "global_load_dwordx4 %11, %19, off offset:2064 sc0 sc1\n\t"
        "global_load_dwordx4 %12, %20, off sc0 sc1\n\t"
        "global_load_dwordx4 %13, %20, off offset:16 sc0 sc1\n\t"
        "global_load_dwordx4 %14, %20, off offset:2048 sc0 sc1\n\t"
        "global_load_dwordx4 %15, %20, off offset:2064 sc0 sc1\n\t"
        "global_load_dword %16, %21, off sc0 sc1\n\t"
        "s_waitcnt vmcnt(0)"
        : "=&v"(g0), "=&v"(g1), "=&v"(g2), "=&v"(g3),
          "=&v"(g4), "=&v"(g5), "=&v"(g6), "=&v"(g7),
          "=&v"(g8), "=&v"(g9), "=&v"(g10), "=&v"(g11),
          "=&v"(g12), "=&v"(g13), "=&v"(g14), "=&v"(g15),
          "=&v"(pv)
        : "v"(b0), "v"(b1), "v"(b2), "v"(b3), "v"(pp)
        : "memory");
}

// ---------------- geometry ----------------
constexpr int BB = 32, SS = 1024, II = 512, HH = 1024;
constexpr int NCOL = 6144;

constexpr size_t OFF_X    = 0;                       // bf16 x   [32768][512]
constexpr size_t SZ_X     = (size_t)BB * SS * II * 2;
constexpr size_t OFF_WINT = OFF_X + SZ_X;            // bf16 WinT [6144][512]
constexpr size_t SZ_WINT  = (size_t)NCOL * II * 2;
constexpr size_t OFF_WREC = OFF_WINT + SZ_WINT;      // bf16 Wrec [2][3072][1024]
constexpr size_t SZ_WREC  = (size_t)2 * 3072 * HH * 2;
constexpr size_t OFF_BIAS = OFF_WREC + SZ_WREC;      // f32 [6144]
constexpr size_t SZ_BIAS  = (size_t)NCOL * 4;
// tagged h tiles: [grp(4)][buf(4)][jg(64)] x [16 b][16 j] u32 (tag<<16|bf16)
constexpr size_t OFF_H    = OFF_BIAS + SZ_BIAS;
constexpr size_t SZ_H     = (size_t)4 * 4 * 64 * 1024;   // 1 MB
constexpr size_t OFF_BAR  = OFF_H + SZ_H;            // progress [4 grp][64 jg][4 wid]
constexpr size_t SZ_BAR   = 4096;
// G layout: [s][dir][jg(64)][bg(2)][b16(16)][gate(3)][j(16)] bf16
constexpr size_t OFF_G    = OFF_BAR + SZ_BAR;
constexpr size_t SZ_G     = (size_t)SS * BB * NCOL * 2;
constexpr size_t WS_NEED  = OFF_G + SZ_G;            // ~456 MB

// gru_rec LDS layout
constexpr int WL_OFF = 0;          // 98304  weights
constexpr int PL_OFF = 98304;      // 26112  partials x2 parity
constexpr int GR_OFF = 124416;     // 6144   G ring, 4 slots x 1536B
constexpr int PF_OFF = 130560;     // 32     partial flags [2 par][4 wave]
constexpr int RD_OFF = 130592;     // 16     G ring ready[4]
constexpr int PG_OFF = 130608;     // 16     G ring progress[4 wave]
constexpr int SMEM_TOT = 130624;
constexpr int PLF = 4 * 3 * 16 * 17;   // floats per parity buffer

// =====================================================================
// prep
// =====================================================================
__global__ void prep_kernel(
    const float* __restrict__ x,
    const float* __restrict__ Wi, const float* __restrict__ Wni,
    const float* __restrict__ Winvi, const float* __restrict__ Wninvi,
    const float* __restrict__ Wh, const float* __restrict__ Wnh,
    const float* __restrict__ Winvh, const float* __restrict__ Wninvh,
    const float* __restrict__ Bg, const float* __restrict__ Bni,
    const float* __restrict__ Binv, const float* __restrict__ Bninvi,
    unsigned short* __restrict__ xb, unsigned short* __restrict__ WinT,
    unsigned short* __restrict__ Wrec, float* __restrict__ bias)
{
    constexpr int NX8  = (BB * SS * II) / 8;
    constexpr int NWI8 = (NCOL * II) / 8;
    constexpr int NWR8 = (2 * 3072 * HH) / 8;
    constexpr int TOT  = NX8 + NWI8 + NWR8 + NCOL;
    for (int i = blockIdx.x * blockDim.x + threadIdx.x; i < TOT;
         i += gridDim.x * blockDim.x) {
        if (i < NX8) {
            const float* sp = x + (size_t)i * 8;
            unsigned short o[8];
#pragma unroll
            for (int j = 0; j < 8; ++j) o[j] = f2bf(sp[j]);
            *(u4v*)(xb + (size_t)i * 8) = pack8(o);
        } else if (i < NX8 + NWI8) {
            int u = i - NX8;
            int n = u >> 6, k0 = (u & 63) * 8;
            const float* src; int stride;
            if (n < 2048)      { src = Wi + n;            stride = 2048; }
            else if (n < 3072) { src = Wni + (n - 2048);  stride = 1024; }
            else if (n < 5120) { src = Winvi + (n - 3072); stride = 2048; }
            else               { src = Wninvi + (n - 5120); stride = 1024; }
            unsigned short o[8];
#pragma unroll
            for (int j = 0; j < 8; ++j) o[j] = f2bf(src[(size_t)(k0 + j) * stride]);
            *(u4v*)(WinT + (size_t)n * 512 + k0) = pack8(o);
        } else if (i < NX8 + NWI8 + NWR8) {
            int u = i - NX8 - NWI8;
            int R = u >> 7, k0 = (u & 127) * 8;
            int dir = R / 3072, n = R % 3072;
            const float* src; int stride;
            if (n < 2048) { src = (dir ? Winvh : Wh) + n;          stride = 2048; }
            else          { src = (dir ? Wninvh : Wnh) + (n - 2048); stride = 1024; }
            unsigned short o[8];
#pragma unroll
            for (int j = 0; j < 8; ++j) o[j] = f2bf(src[(size_t)(k0 + j) * stride]);
            *(u4v*)(Wrec + (size_t)R * 1024 + k0) = pack8(o);
        } else {
            int c = i - NX8 - NWI8 - NWR8;
            int dir = c / 3072, cc = c % 3072;
            bias[c] = (cc < 2048) ? (dir ? Binv : Bg)[cc]
                                  : (dir ? Bninvi : Bni)[cc - 2048];
        }
    }
}

// =====================================================================
// gemm_in (unchanged)
// =====================================================================
#define GLL16(gp, lp) __builtin_amdgcn_global_load_lds( \
    (const __attribute__((address_space(1))) void*)(gp), \
    (__attribute__((address_space(3))) void*)(lp), 16, 0, 0)

__global__ __launch_bounds__(256, 2) void gemm_in(
    const unsigned short* __restrict__ xb,
    const unsigned short* __restrict__ WinT,
    const float* __restrict__ bias,
    unsigned short* __restrict__ G)
{
    __shared__ char smem[32768];
    char* As = smem;
    char* Bs = smem + 16384;
    const int tid = threadIdx.x, lane = tid & 63, wid = tid >> 6;
    int wg = blockIdx.x;
    int swz = (wg & 7) * 1536 + (wg >> 3);
    const int m0 = (swz & 255) * 128, n0 = (swz >> 8) * 128;
    const int l15 = lane & 15, hi = lane >> 4;
    const int mw = (wid & 1) * 64, nw = (wid >> 1) * 64;

    f4v acc[4][4] = {};

    const char* xrow = (const char*)xb;
    const char* wrow = (const char*)WinT;

    for (int kt = 0; kt < 8; ++kt) {
        const int kb0 = kt * 128;
#pragma unroll
        for (int r = 0; r < 4; ++r) {
            int q = wid * 4 + r;
            int o = q * 1024 + lane * 16;
            int row = o >> 7;
            int kbs = (o ^ ((row & 7) << 4)) & 127;
            GLL16(xrow + (size_t)(m0 + row) * 1024 + kb0 + kbs, As + q * 1024);
            GLL16(wrow + (size_t)(n0 + row) * 1024 + kb0 + kbs, Bs + q * 1024);
        }
        __syncthreads();
#pragma unroll
        for (int kc = 0; kc < 2; ++kc) {
            s8v a[4], b[4];
#pragma unroll
            for (int mt = 0; mt < 4; ++mt) {
                int row = mw + mt * 16 + l15;
                int off = (row << 7) + kc * 64 + hi * 16;
                a[mt] = *(const s8v*)(As + (off ^ ((row & 7) << 4)));
            }
#pragma unroll
            for (int nt = 0; nt < 4; ++nt) {
                int row = nw + nt * 16 + l15;
                int off = (row << 7) + kc * 64 + hi * 16;
                b[nt] = *(const s8v*)(Bs + (off ^ ((row & 7) << 4)));
            }
#pragma unroll
            for (int mt = 0; mt < 4; ++mt)
#pragma unroll
                for (int nt = 0; nt < 4; ++nt)
                    acc[mt][nt] = __builtin_amdgcn_mfma_f32_16x16x32_bf16(
                        a[mt], b[nt], acc[mt][nt], 0, 0, 0);
        }
        __syncthreads();
    }
#pragma unroll
    for (int mt = 0; mt < 4; ++mt) {
#pragma unroll
        for (int rg = 0; rg < 4; ++rg) {
            int m = m0 + mw + mt * 16 + hi * 4 + rg;
            int bi = m >> 10, si = m & 1023;
            int bg = bi >> 4, b16 = bi & 15;
#pragma unroll
            for (int nt = 0; nt < 4; ++nt) {
                int n = n0 + nw + nt * 16 + l15;
                int dir = (n >= 3072);
                int rem = n - dir * 3072;
                int gate = rem >> 10, col = rem & 1023;
                int jg = col >> 4, j = col & 15;
                size_t idx = (((((size_t)si * 2 + dir) * 64 + jg) * 2 + bg) * 16
                              + b16) * 48 + gate * 16 + j;
                G[idx] = f2bf(acc[mt][nt][rg] + bias[n]);
            }
        }
    }
}

// =====================================================================
// gru_rec: persistent bidirectional GRU, 256 blocks (1/CU), 320 threads:
// waves 0-3 compute, wave 4 = G prefetcher. h exchange = TAG-IN-DATA
// (u32 = tag<<16 | bf16), 4-deep ring, consumer-progress backpressure.
// No producer drain, no flags, no in-loop __syncthreads.
// =====================================================================
#define UNPACK8(dst, A, B) { u4v d_;                                   \
    d_[0] = __builtin_amdgcn_perm(A[1], A[0], 0x05040100u);            \
    d_[1] = __builtin_amdgcn_perm(A[3], A[2], 0x05040100u);            \
    d_[2] = __builtin_amdgcn_perm(B[1], B[0], 0x05040100u);            \
    d_[3] = __builtin_amdgcn_perm(B[3], B[2], 0x05040100u);            \
    dst = __builtin_bit_cast(s8v, d_); }

__global__ __launch_bounds__(320, 1) void gru_rec(
    const unsigned short* __restrict__ G,     // [s][dir][jg][bg][b16][gate][j]
    const unsigned short* __restrict__ Wrec,  // [2][3072][1024]
    const float* __restrict__ Bnh,
    const float* __restrict__ Bninvh,
    unsigned int* __restrict__ hbuf32,        // tagged tiles [grp][buf4][jg][16][16]
    float* __restrict__ out,                  // [32][1024][2048] + ht [32][2048]
    unsigned int* __restrict__ prog)          // [4 grp][64 jg][4 wid]
{
    extern __shared__ char smem[];
    char* wl = smem + WL_OFF;
    float* pl = (float*)(smem + PL_OFF);
    unsigned short* gring = (unsigned short*)(smem + GR_OFF);
    volatile int* pflag = (volatile int*)(smem + PF_OFF);
    volatile int* gready = (volatile int*)(smem + RD_OFF);
    volatile int* gprog  = (volatile int*)(smem + PG_OFF);

    const int tid = threadIdx.x, lane = tid & 63, wid = tid >> 6;
    const int bid = blockIdx.x;
    const int dir = bid >> 7, bg = (bid >> 6) & 1, jg = bid & 63;
    const int grp = dir * 2 + bg;
    const int jbase = jg * 16, bb = bg * 16;
    const int l15 = lane & 15, hi = lane >> 4;

    // ---- prologue ----
    if (tid < 4) { gready[tid] = -1; gprog[tid] = -1; }
    if (tid >= 4 && tid < 12) pflag[tid - 4] = -1;
    if (tid < 256) {
        const char* wsrc = (const char*)Wrec;
        for (int q = 0; q < 24; ++q) {
            int o = (q * 256 + tid) * 16;
            int c = o >> 11;
            int kb = (o ^ ((c & 7) << 4)) & 2047;
            int n = dir * 3072 + (c >> 4) * 1024 + jbase + (c & 15);
            *(u4v*)(wl + o) = *(const u4v*)(wsrc + (size_t)n * 2048 + kb);
        }
    }
    const int b_l = tid >> 4, j_l = tid & 15;
    const float bnh = (dir ? Bninvh : Bnh)[jbase + (j_l & 15)];
    __syncthreads();   // the ONLY block-wide barrier

    const size_t gstride_b = (size_t)2 * 64 * 2 * 768 * 2;   // bytes per s
    const char* gcb = (const char*)G + (((size_t)dir * 64 + jg) * 2 + bg) * 1536;

    if (wid == 4) {
        // ---------------- G prefetch wave ----------------
        char* grb = (char*)gring;
        for (int t = 0; t < 1024; ++t) {
            const int slot = t & 3;
            if (t >= 4) {
                int v;
                do { v = gprog[lane & 3]; } while (!__all(v >= t - 4));
            }
            const int gpos = dir ? (1023 - t) : t;
            const char* src = gcb + (size_t)gpos * gstride_b + lane * 32;
            if (lane < 48) {
                u4v d0 = *(const u4v*)(src);
                u4v d1 = *(const u4v*)(src + 16);
                *(u4v*)(grb + slot * 1536 + lane * 32) = d0;
                *(u4v*)(grb + slot * 1536 + lane * 32 + 16) = d1;
            }
            asm volatile("s_waitcnt lgkmcnt(0) vmcnt(0)" ::: "memory");
            if (lane == 0) gready[slot] = t;
        }
        return;
    }

    // ---------------- compute waves (0..3) ----------------
    float h_old = 0.0f;

    // per-wave gather geometry (tagged tiles, 1 KB each)
    const char* hregion = (const char*)hbuf32;           // byte base
    // backpressure read addr: progress of wave (jg>>4) of block 'lane'
    const unsigned int* pp = prog + ((size_t)grp * 64 + lane) * 4 + (jg >> 4);
    unsigned int* ppub = prog + ((size_t)grp * 64 + jg) * 4 + wid;
    // h store addr (u32 index)
    unsigned int* hstore_base = hbuf32 + (size_t)grp * 4 * 64 * 256
                                + (size_t)jg * 256 + b_l * 16 + j_l;

    for (int s = 0; s < 1024; ++s) {
        const int par = s & 1;
        float* plc = pl + par * PLF;

        // ---- G for this step from the LDS ring ----
        const int slot = s & 3;
        {
            int r;
            do { r = gready[slot]; } while (r != s);
        }
        asm volatile("" ::: "memory");
        const int gb = slot * 768 + b_l * 48 + j_l;
        unsigned short gr = gring[gb];
        unsigned short gz = gring[gb + 16];
        unsigned short gn = gring[gb + 32];
        asm volatile("s_waitcnt lgkmcnt(0)" ::: "memory");
        if (lane == 0) gprog[wid] = s;

        float rsum = 0.f, zsum = 0.f, nsum = 0.f;
        unsigned pv = 0;

        if (s > 0) {
            // ---- merged poll+gather of tagged h tiles ----
            const int rbuf = (s - 1) & 3;
            const char* hb = hregion
                + ((size_t)(grp * 4 + rbuf) * 64 + wid * 16) * 1024
                + (size_t)(hi >> 1) * 1024 + l15 * 64 + (hi & 1) * 32;
            const unsigned tagpat = (unsigned)(s - 1) << 16;
            u4v tp; tp[0] = tagpat; tp[1] = tagpat; tp[2] = tagpat; tp[3] = tagpat;
            u4v g0, g1, g2, g3, g4, g5, g6, g7,
                g8, g9, g10, g11, g12, g13, g14, g15;
            for (;;) {
                gather_tagged(hb, hb + 4096, hb + 8192, hb + 12288, pp,
                              g0, g1, g2, g3, g4, g5, g6, g7,
                              g8, g9, g10, g11, g12, g13, g14, g15, pv);
                u4v a = (g0 ^ tp) | (g1 ^ tp) | (g2 ^ tp) | (g3 ^ tp)
                      | (g4 ^ tp) | (g5 ^ tp) | (g6 ^ tp) | (g7 ^ tp)
                      | (g8 ^ tp) | (g9 ^ tp) | (g10 ^ tp) | (g11 ^ tp)
                      | (g12 ^ tp) | (g13 ^ tp) | (g14 ^ tp) | (g15 ^ tp);
                unsigned bad = (a[0] | a[1] | a[2] | a[3]) & 0xffff0000u;
                if (__all(bad == 0)) break;
            }
            // progress publish: this wave's step-(s-1) data is in registers
            if (lane == 0) store_wt(ppub, (unsigned)s);

            // ---- unpack tagged u32 -> bf16 A-frags ----
            s8v af[8];
            UNPACK8(af[0], g0, g1);   UNPACK8(af[1], g2, g3);
            UNPACK8(af[2], g4, g5);   UNPACK8(af[3], g6, g7);
            UNPACK8(af[4], g8, g9);   UNPACK8(af[5], g10, g11);
            UNPACK8(af[6], g12, g13); UNPACK8(af[7], g14, g15);

            f4v acc[3] = {};
#pragma unroll
            for (int p = 0; p < 3; ++p) {
                int c = p * 16 + l15;
                int cbase = c << 11;
                int sw = (c & 7) << 4;
#pragma unroll
                for (int kc = 0; kc < 8; ++kc) {
                    int off = cbase + (wid << 9) + kc * 64 + hi * 16;
                    s8v bf = *(const s8v*)(wl + (off ^ sw));
                    acc[p] = __builtin_amdgcn_mfma_f32_16x16x32_bf16(
                        af[kc], bf, acc[p], 0, 0, 0);
                }
            }
#pragma unroll
            for (int p = 0; p < 3; ++p)
#pragma unroll
                for (int rg = 0; rg < 4; ++rg)
                    plc[((wid * 3 + p) * 16 + hi * 4 + rg) * 17 + l15] = acc[p][rg];
            asm volatile("s_waitcnt lgkmcnt(0)" ::: "memory");
            if (lane == 0) pflag[par * 4 + wid] = s;

            // ---- barrier-free reduce sync across the 4 compute waves ----
            {
                int f0, f1, f2, f3;
                do {
                    f0 = pflag[par * 4 + 0]; f1 = pflag[par * 4 + 1];
                    f2 = pflag[par * 4 + 2]; f3 = pflag[par * 4 + 3];
                } while (f0 < s || f1 < s || f2 < s || f3 < s);
            }
            asm volatile("" ::: "memory");
#pragma unroll
            for (int w = 0; w < 4; ++w) {
                rsum += plc[((w * 3 + 0) * 16 + b_l) * 17 + j_l];
                zsum += plc[((w * 3 + 1) * 16 + b_l) * 17 + j_l];
                nsum += plc[((w * 3 + 2) * 16 + b_l) * 17 + j_l];
            }
        }

        float rv = sigm(rsum + bf2f(gr));
        float zv = sigm(zsum + bf2f(gz));
        float nv = tanh_fast(bf2f(gn) + rv * (nsum + bnh));
        float hn = (1.0f - zv) * nv + zv * h_old;
        h_old = hn;

        if (s < 1023) {
            // backpressure: readers of my tile must have consumed s-4 data.
            // pv was piggybacked on this step's gather — steady-state passes.
            if (s >= 4) {
                while (!__all((int)pv >= s - 3)) pv = poll_load(pp);
            }
            unsigned val = ((unsigned)s << 16) | (unsigned)f2bf(hn);
            store_wt(hstore_base + (size_t)(s & 3) * 64 * 256, val);
        }
        // out: plain cached store, completely off the critical path
        const int s_out = dir ? (1023 - s) : s;
        out[((size_t)(bb + b_l) * SS + s_out) * 2048 + dir * 1024 + jbase + j_l] = hn;
        if (s == 1023)
            out[(size_t)BB * SS * 2048 + (size_t)(bb + b_l) * 2048 +
                dir * 1024 + jbase + j_l] = hn;
    }
}

// =====================================================================
extern "C" void kernel_launch(void* const* d_in, const int* in_sizes, int n_in,
                              void* d_out, int out_size, void* d_ws, size_t ws_size,
                              hipStream_t stream)
{
    if (n_in < 15) return;
    const float* x      = (const float*)d_in[0];
    const float* Wi     = (const float*)d_in[1];
    const float* Wh     = (const float*)d_in[2];
    const float* Bg     = (const float*)d_in[3];
    const float* Wni    = (const float*)d_in[4];
    const float* Wnh    = (const float*)d_in[5];
    const float* Bni    = (const float*)d_in[6];
    const float* Bnh    = (const float*)d_in[7];
    const float* Winvi  = (const float*)d_in[8];
    const float* Winvh  = (const float*)d_in[9];
    const float* Binv   = (const float*)d_in[10];
    const float* Wninvi = (const float*)d_in[11];
    const float* Wninvh = (const float*)d_in[12];
    const float* Bninvi = (const float*)d_in[13];
    const float* Bninvh = (const float*)d_in[14];

    if (ws_size < WS_NEED) {
        hipMemsetAsync(d_out, 0, (size_t)out_size * 4, stream);
        return;
    }
    char* ws = (char*)d_ws;
    unsigned short* xb   = (unsigned short*)(ws + OFF_X);
    unsigned short* WinT = (unsigned short*)(ws + OFF_WINT);
    unsigned short* Wrec = (unsigned short*)(ws + OFF_WREC);
    float*          bias = (float*)(ws + OFF_BIAS);
    unsigned int*   hbuf = (unsigned int*)(ws + OFF_H);
    unsigned int*   bar  = (unsigned int*)(ws + OFF_BAR);
    unsigned short* G    = (unsigned short*)(ws + OFF_G);

    hipMemsetAsync(ws + OFF_BAR, 0, SZ_BAR, stream);

    prep_kernel<<<4096, 256, 0, stream>>>(
        x, Wi, Wni, Winvi, Wninvi, Wh, Wnh, Winvh, Wninvh,
        Bg, Bni, Binv, Bninvi, xb, WinT, Wrec, bias);

    gemm_in<<<12288, 256, 0, stream>>>(xb, WinT, bias, G);

    hipFuncSetAttribute(reinterpret_cast<const void*>(&gru_rec),
                        hipFuncAttributeMaxDynamicSharedMemorySize, SMEM_TOT);
    gru_rec<<<256, 320, SMEM_TOT, stream>>>(
        G, Wrec, Bnh, Bninvh, hbuf, (float*)d_out, bar);
}

// Round 7
// 3850.634 us; speedup vs baseline: 2.1542x; 2.1542x over previous
//
#include <hip/hip_runtime.h>
#include <cstdint>
#include <cstddef>

typedef __attribute__((ext_vector_type(8))) short s8v;          // 8 bf16
typedef __attribute__((ext_vector_type(4))) float f4v;
typedef __attribute__((ext_vector_type(4))) unsigned int u4v;

#define DEVFN __device__ __forceinline__

DEVFN unsigned short f2bf(float f) {
    unsigned int u = __builtin_bit_cast(unsigned int, f);
    return (unsigned short)((u + 0x7FFFu + ((u >> 16) & 1u)) >> 16);
}
DEVFN float bf2f(unsigned short h) {
    unsigned int u = ((unsigned int)h) << 16;
    return __builtin_bit_cast(float, u);
}
DEVFN float sigm(float x) { return 1.0f / (1.0f + __expf(-x)); }
DEVFN float tanh_fast(float x) { float e = __expf(2.0f * x); return 1.0f - 2.0f / (e + 1.0f); }

DEVFN u4v pack8(const unsigned short o[8]) {
    u4v v;
    v[0] = (unsigned)o[0] | ((unsigned)o[1] << 16);
    v[1] = (unsigned)o[2] | ((unsigned)o[3] << 16);
    v[2] = (unsigned)o[4] | ((unsigned)o[5] << 16);
    v[3] = (unsigned)o[6] | ((unsigned)o[7] << 16);
    return v;
}

// device-scope (LLC) write-through store — visible across XCDs, no fence.
DEVFN void store_wt(unsigned int* p, unsigned int v) {
    asm volatile("global_store_dword %0, %1, off sc0 sc1"
                 :: "v"(p), "v"(v) : "memory");
}
// LLC-direct flag read (bypasses stale L1/L2).
DEVFN unsigned poll_load(const unsigned int* p) {
    unsigned v;
    asm volatile("global_load_dword %0, %1, off sc0 sc1\n\t"
                 "s_waitcnt vmcnt(0)"
                 : "=v"(v) : "v"(p) : "memory");
    return v;
}
// 8x dwordx4 LLC-direct tile gather + drain.
DEVFN void gather_h(const void* p0, const void* p1,
                    u4v& a0, u4v& a1, u4v& a2, u4v& a3,
                    u4v& a4, u4v& a5, u4v& a6, u4v& a7) {
    asm volatile(
        "global_load_dwordx4 %0, %8, off sc0 sc1\n\t"
        "global_load_dwordx4 %1, %8, off offset:1024 sc0 sc1\n\t"
        "global_load_dwordx4 %2, %8, off offset:2048 sc0 sc1\n\t"
        "global_load_dwordx4 %3, %8, off offset:3072 sc0 sc1\n\t"
        "global_load_dwordx4 %4, %9, off sc0 sc1\n\t"
        "global_load_dwordx4 %5, %9, off offset:1024 sc0 sc1\n\t"
        "global_load_dwordx4 %6, %9, off offset:2048 sc0 sc1\n\t"
        "global_load_dwordx4 %7, %9, off offset:3072 sc0 sc1\n\t"
        "s_waitcnt vmcnt(0)"
        : "=&v"(a0), "=&v"(a1), "=&v"(a2), "=&v"(a3),
          "=&v"(a4), "=&v"(a5), "=&v"(a6), "=&v"(a7)
        : "v"(p0), "v"(p1)
        : "memory");
}

// ---------------- geometry ----------------
constexpr int BB = 32, SS = 1024, II = 512, HH = 1024;
constexpr int NCOL = 6144;

constexpr size_t OFF_X    = 0;                       // bf16 x   [32768][512]
constexpr size_t SZ_X     = (size_t)BB * SS * II * 2;
constexpr size_t OFF_WINT = OFF_X + SZ_X;            // bf16 WinT [6144][512]
constexpr size_t SZ_WINT  = (size_t)NCOL * II * 2;
constexpr size_t OFF_WREC = OFF_WINT + SZ_WINT;      // bf16 Wrec [2][3072][1024]
constexpr size_t SZ_WREC  = (size_t)2 * 3072 * HH * 2;
constexpr size_t OFF_BIAS = OFF_WREC + SZ_WREC;      // f32 [6144]
constexpr size_t SZ_BIAS  = (size_t)NCOL * 4;
// h tiles: [dir][buf][bg][jg(64)][b16(16)][j16(16)] bf16 — 512 B per tile
constexpr size_t OFF_H    = OFF_BIAS + SZ_BIAS;
constexpr size_t SZ_H     = (size_t)2 * 2 * 2 * 64 * 512;
constexpr size_t OFF_BAR  = OFF_H + SZ_H;            // flags [4 groups][64 jg][4 wave]
constexpr size_t SZ_BAR   = 4096;
// G layout: [s][dir][jg(64)][bg(2)][b16(16)][gate(3)][j(16)] bf16
constexpr size_t OFF_G    = OFF_BAR + SZ_BAR;
constexpr size_t SZ_G     = (size_t)SS * BB * NCOL * 2;
constexpr size_t WS_NEED  = OFF_G + SZ_G;            // ~455 MB

// gru_rec LDS layout
constexpr int WL_OFF = 0;          // 98304  weights
constexpr int PL_OFF = 98304;      // 26112  partials x2 parity
constexpr int GR_OFF = 124416;     // 6144   G ring, 4 slots x 1536B
constexpr int PF_OFF = 130560;     // 32     partial flags [2 par][4 wave]
constexpr int RD_OFF = 130592;     // 16     G ring ready[4]
constexpr int PG_OFF = 130608;     // 16     G ring progress[4 wave]
constexpr int SMEM_TOT = 130624;
constexpr int PLF = 4 * 3 * 16 * 17;   // floats per parity buffer

// =====================================================================
// prep
// =====================================================================
__global__ void prep_kernel(
    const float* __restrict__ x,
    const float* __restrict__ Wi, const float* __restrict__ Wni,
    const float* __restrict__ Winvi, const float* __restrict__ Wninvi,
    const float* __restrict__ Wh, const float* __restrict__ Wnh,
    const float* __restrict__ Winvh, const float* __restrict__ Wninvh,
    const float* __restrict__ Bg, const float* __restrict__ Bni,
    const float* __restrict__ Binv, const float* __restrict__ Bninvi,
    unsigned short* __restrict__ xb, unsigned short* __restrict__ WinT,
    unsigned short* __restrict__ Wrec, float* __restrict__ bias)
{
    constexpr int NX8  = (BB * SS * II) / 8;
    constexpr int NWI8 = (NCOL * II) / 8;
    constexpr int NWR8 = (2 * 3072 * HH) / 8;
    constexpr int TOT  = NX8 + NWI8 + NWR8 + NCOL;
    for (int i = blockIdx.x * blockDim.x + threadIdx.x; i < TOT;
         i += gridDim.x * blockDim.x) {
        if (i < NX8) {
            const float* sp = x + (size_t)i * 8;
            unsigned short o[8];
#pragma unroll
            for (int j = 0; j < 8; ++j) o[j] = f2bf(sp[j]);
            *(u4v*)(xb + (size_t)i * 8) = pack8(o);
        } else if (i < NX8 + NWI8) {
            int u = i - NX8;
            int n = u >> 6, k0 = (u & 63) * 8;
            const float* src; int stride;
            if (n < 2048)      { src = Wi + n;            stride = 2048; }
            else if (n < 3072) { src = Wni + (n - 2048);  stride = 1024; }
            else if (n < 5120) { src = Winvi + (n - 3072); stride = 2048; }
            else               { src = Wninvi + (n - 5120); stride = 1024; }
            unsigned short o[8];
#pragma unroll
            for (int j = 0; j < 8; ++j) o[j] = f2bf(src[(size_t)(k0 + j) * stride]);
            *(u4v*)(WinT + (size_t)n * 512 + k0) = pack8(o);
        } else if (i < NX8 + NWI8 + NWR8) {
            int u = i - NX8 - NWI8;
            int R = u >> 7, k0 = (u & 127) * 8;
            int dir = R / 3072, n = R % 3072;
            const float* src; int stride;
            if (n < 2048) { src = (dir ? Winvh : Wh) + n;          stride = 2048; }
            else          { src = (dir ? Wninvh : Wnh) + (n - 2048); stride = 1024; }
            unsigned short o[8];
#pragma unroll
            for (int j = 0; j < 8; ++j) o[j] = f2bf(src[(size_t)(k0 + j) * stride]);
            *(u4v*)(Wrec + (size_t)R * 1024 + k0) = pack8(o);
        } else {
            int c = i - NX8 - NWI8 - NWR8;
            int dir = c / 3072, cc = c % 3072;
            bias[c] = (cc < 2048) ? (dir ? Binv : Bg)[cc]
                                  : (dir ? Bninvi : Bni)[cc - 2048];
        }
    }
}

// =====================================================================
// gemm_in (unchanged)
// =====================================================================
#define GLL16(gp, lp) __builtin_amdgcn_global_load_lds( \
    (const __attribute__((address_space(1))) void*)(gp), \
    (__attribute__((address_space(3))) void*)(lp), 16, 0, 0)

__global__ __launch_bounds__(256, 2) void gemm_in(
    const unsigned short* __restrict__ xb,
    const unsigned short* __restrict__ WinT,
    const float* __restrict__ bias,
    unsigned short* __restrict__ G)
{
    __shared__ char smem[32768];
    char* As = smem;
    char* Bs = smem + 16384;
    const int tid = threadIdx.x, lane = tid & 63, wid = tid >> 6;
    int wg = blockIdx.x;
    int swz = (wg & 7) * 1536 + (wg >> 3);
    const int m0 = (swz & 255) * 128, n0 = (swz >> 8) * 128;
    const int l15 = lane & 15, hi = lane >> 4;
    const int mw = (wid & 1) * 64, nw = (wid >> 1) * 64;

    f4v acc[4][4] = {};

    const char* xrow = (const char*)xb;
    const char* wrow = (const char*)WinT;

    for (int kt = 0; kt < 8; ++kt) {
        const int kb0 = kt * 128;
#pragma unroll
        for (int r = 0; r < 4; ++r) {
            int q = wid * 4 + r;
            int o = q * 1024 + lane * 16;
            int row = o >> 7;
            int kbs = (o ^ ((row & 7) << 4)) & 127;
            GLL16(xrow + (size_t)(m0 + row) * 1024 + kb0 + kbs, As + q * 1024);
            GLL16(wrow + (size_t)(n0 + row) * 1024 + kb0 + kbs, Bs + q * 1024);
        }
        __syncthreads();
#pragma unroll
        for (int kc = 0; kc < 2; ++kc) {
            s8v a[4], b[4];
#pragma unroll
            for (int mt = 0; mt < 4; ++mt) {
                int row = mw + mt * 16 + l15;
                int off = (row << 7) + kc * 64 + hi * 16;
                a[mt] = *(const s8v*)(As + (off ^ ((row & 7) << 4)));
            }
#pragma unroll
            for (int nt = 0; nt < 4; ++nt) {
                int row = nw + nt * 16 + l15;
                int off = (row << 7) + kc * 64 + hi * 16;
                b[nt] = *(const s8v*)(Bs + (off ^ ((row & 7) << 4)));
            }
#pragma unroll
            for (int mt = 0; mt < 4; ++mt)
#pragma unroll
                for (int nt = 0; nt < 4; ++nt)
                    acc[mt][nt] = __builtin_amdgcn_mfma_f32_16x16x32_bf16(
                        a[mt], b[nt], acc[mt][nt], 0, 0, 0);
        }
        __syncthreads();
    }
#pragma unroll
    for (int mt = 0; mt < 4; ++mt) {
#pragma unroll
        for (int rg = 0; rg < 4; ++rg) {
            int m = m0 + mw + mt * 16 + hi * 4 + rg;
            int bi = m >> 10, si = m & 1023;
            int bg = bi >> 4, b16 = bi & 15;
#pragma unroll
            for (int nt = 0; nt < 4; ++nt) {
                int n = n0 + nw + nt * 16 + l15;
                int dir = (n >= 3072);
                int rem = n - dir * 3072;
                int gate = rem >> 10, col = rem & 1023;
                int jg = col >> 4, j = col & 15;
                size_t idx = (((((size_t)si * 2 + dir) * 64 + jg) * 2 + bg) * 16
                              + b16) * 48 + gate * 16 + j;
                G[idx] = f2bf(acc[mt][nt][rg] + bias[n]);
            }
        }
    }
}

// =====================================================================
// gru_rec: persistent bidirectional GRU recurrence, 256 blocks (1/CU),
// 320 threads: waves 0-3 compute, wave 4 = G prefetcher (own vmcnt!).
// r5 structure (narrow flag poll + single gather). r7 fix: producer drain
// covers ONLY h stores; out stores (nontemporal) issue AFTER flag publish.
// =====================================================================
__global__ __launch_bounds__(320, 1) void gru_rec(
    const unsigned short* __restrict__ G,     // [s][dir][jg][bg][b16][gate][j]
    const unsigned short* __restrict__ Wrec,  // [2][3072][1024]
    const float* __restrict__ Bnh,
    const float* __restrict__ Bninvh,
    unsigned short* __restrict__ hbuf,        // bf16 tiles [dir][buf][bg][jg][16][16]
    float* __restrict__ out,                  // [32][1024][2048] + ht [32][2048]
    unsigned int* __restrict__ flags)         // [4 groups][64 jg][4 wave]
{
    extern __shared__ char smem[];
    char* wl = smem + WL_OFF;
    float* pl = (float*)(smem + PL_OFF);
    unsigned short* gring = (unsigned short*)(smem + GR_OFF);
    volatile int* pflag = (volatile int*)(smem + PF_OFF);
    volatile int* gready = (volatile int*)(smem + RD_OFF);
    volatile int* gprog  = (volatile int*)(smem + PG_OFF);

    const int tid = threadIdx.x, lane = tid & 63, wid = tid >> 6;
    const int bid = blockIdx.x;
    const int dir = bid >> 7, bg = (bid >> 6) & 1, jg = bid & 63;
    const int jbase = jg * 16, bb = bg * 16;
    const int l15 = lane & 15, hi = lane >> 4;
    unsigned int* fl = flags + ((dir * 2 + bg) << 8);

    // ---- prologue: init LDS flags; stage 3 weight panels into LDS ----
    if (tid < 4) { gready[tid] = -1; gprog[tid] = -1; }
    if (tid >= 4 && tid < 12) pflag[tid - 4] = -1;
    if (tid < 256) {
        const char* wsrc = (const char*)Wrec;
        for (int q = 0; q < 24; ++q) {
            int o = (q * 256 + tid) * 16;
            int c = o >> 11;
            int kb = (o ^ ((c & 7) << 4)) & 2047;
            int n = dir * 3072 + (c >> 4) * 1024 + jbase + (c & 15);
            *(u4v*)(wl + o) = *(const u4v*)(wsrc + (size_t)n * 2048 + kb);
        }
    }
    const int b_l = tid >> 4, j_l = tid & 15;
    const float bnh = (dir ? Bninvh : Bnh)[jbase + (j_l & 15)];
    __syncthreads();   // the ONLY block-wide barrier

    const size_t gstride_b = (size_t)2 * 64 * 2 * 768 * 2;   // bytes per s
    const char* gcb = (const char*)G + (((size_t)dir * 64 + jg) * 2 + bg) * 1536;

    if (wid == 4) {
        // ---------------- G prefetch wave ----------------
        char* grb = (char*)gring;
        for (int t = 0; t < 1024; ++t) {
            const int slot = t & 3;
            if (t >= 4) {
                int v;
                do { v = gprog[lane & 3]; } while (!__all(v >= t - 4));
            }
            const int gpos = dir ? (1023 - t) : t;
            const char* src = gcb + (size_t)gpos * gstride_b + lane * 32;
            if (lane < 48) {
                u4v d0 = *(const u4v*)(src);
                u4v d1 = *(const u4v*)(src + 16);
                *(u4v*)(grb + slot * 1536 + lane * 32) = d0;
                *(u4v*)(grb + slot * 1536 + lane * 32 + 16) = d1;
            }
            asm volatile("s_waitcnt lgkmcnt(0) vmcnt(0)" ::: "memory");
            if (lane == 0) gready[slot] = t;
        }
        return;
    }

    // ---------------- compute waves (0..3) ----------------
    float h_old = 0.0f;
    unsigned int* hbuf32 = (unsigned int*)hbuf;

    for (int s = 0; s < 1024; ++s) {
        const int par = s & 1;
        float* plc = pl + par * PLF;

        // ---- G for this step from the LDS ring ----
        const int slot = s & 3;
        {
            int r;
            do { r = gready[slot]; } while (r != s);
        }
        asm volatile("" ::: "memory");
        const int gb = slot * 768 + b_l * 48 + j_l;
        unsigned short gr = gring[gb];
        unsigned short gz = gring[gb + 16];
        unsigned short gn = gring[gb + 32];
        asm volatile("s_waitcnt lgkmcnt(0)" ::: "memory");
        if (lane == 0) gprog[wid] = s;

        float rsum = 0.f, zsum = 0.f, nsum = 0.f;
        if (s > 0) {
            // ---- wave-subset poll: 16 producer blocks x 4 wave-flags ----
            // (narrow: 1 dword/lane per retry — cheap to spin; data gathered once)
            const unsigned tgt = (unsigned)s;
            const unsigned int* fp = fl + wid * 64 + lane;
            unsigned v;
            do { v = poll_load(fp); } while (!__all(v >= tgt));

            // ---- gather h tiles (contiguous 512B per producer block) ----
            const int rbuf = par ^ 1;
            const char* hb = (const char*)hbuf +
                ((((size_t)(dir * 2 + rbuf) * 2 + bg) * 64)
                 + (size_t)(wid * 16 + (hi >> 1))) * 512
                + l15 * 32 + (hi & 1) * 16;
            u4v u[8];
            gather_h(hb, hb + 4096, u[0], u[1], u[2], u[3],
                     u[4], u[5], u[6], u[7]);

            f4v acc[3] = {};
#pragma unroll
            for (int p = 0; p < 3; ++p) {
                int c = p * 16 + l15;
                int cbase = c << 11;
                int sw = (c & 7) << 4;
#pragma unroll
                for (int kc = 0; kc < 8; ++kc) {
                    int off = cbase + (wid << 9) + kc * 64 + hi * 16;
                    s8v bf = *(const s8v*)(wl + (off ^ sw));
                    acc[p] = __builtin_amdgcn_mfma_f32_16x16x32_bf16(
                        __builtin_bit_cast(s8v, u[kc]), bf, acc[p], 0, 0, 0);
                }
            }
#pragma unroll
            for (int p = 0; p < 3; ++p)
#pragma unroll
                for (int rg = 0; rg < 4; ++rg)
                    plc[((wid * 3 + p) * 16 + hi * 4 + rg) * 17 + l15] = acc[p][rg];
            asm volatile("s_waitcnt lgkmcnt(0)" ::: "memory");
            if (lane == 0) pflag[par * 4 + wid] = s;

            // ---- barrier-free reduce sync: wait all 4 compute waves ----
            {
                int f0, f1, f2, f3;
                do {
                    f0 = pflag[par * 4 + 0]; f1 = pflag[par * 4 + 1];
                    f2 = pflag[par * 4 + 2]; f3 = pflag[par * 4 + 3];
                } while (f0 < s || f1 < s || f2 < s || f3 < s);
            }
            asm volatile("" ::: "memory");
#pragma unroll
            for (int w = 0; w < 4; ++w) {
                rsum += plc[((w * 3 + 0) * 16 + b_l) * 17 + j_l];
                zsum += plc[((w * 3 + 1) * 16 + b_l) * 17 + j_l];
                nsum += plc[((w * 3 + 2) * 16 + b_l) * 17 + j_l];
            }
        }

        float rv = sigm(rsum + bf2f(gr));
        float zv = sigm(zsum + bf2f(gz));
        float nv = tanh_fast(bf2f(gn) + rv * (nsum + bnh));
        float hn = (1.0f - zv) * nv + zv * h_old;
        h_old = hn;

        if (s < 1023) {
            // h tile store (contiguous 512B, write-through pairs) ...
            unsigned short hbv = f2bf(hn);
            unsigned int other = (unsigned int)(unsigned short)__shfl_xor((int)hbv, 1);
            if (!(tid & 1)) {
                size_t w32 = ((((size_t)(dir * 2 + par) * 2 + bg) * 64 + jg) * 128)
                             + b_l * 8 + (j_l >> 1);
                store_wt(hbuf32 + w32, (unsigned)hbv | (other << 16));
            }
            // ... drain ONLY these h stores (prev step's out-stores retired
            // long ago during this step's poll/gather) ...
            asm volatile("s_waitcnt vmcnt(0)" ::: "memory");
            // ... and publish the flag immediately.
            if (lane == 0)
                store_wt(&fl[jg * 4 + wid], (unsigned)(s + 1));
        }

        // out: nontemporal store AFTER flag publish — write-allocate fetch and
        // store ack are fully off the critical path now.
        const int s_out = dir ? (1023 - s) : s;
        __builtin_nontemporal_store(hn,
            &out[((size_t)(bb + b_l) * SS + s_out) * 2048 + dir * 1024 + jbase + j_l]);
        if (s == 1023)
            __builtin_nontemporal_store(hn,
                &out[(size_t)BB * SS * 2048 + (size_t)(bb + b_l) * 2048 +
                     dir * 1024 + jbase + j_l]);
    }
}

// =====================================================================
extern "C" void kernel_launch(void* const* d_in, const int* in_sizes, int n_in,
                              void* d_out, int out_size, void* d_ws, size_t ws_size,
                              hipStream_t stream)
{
    if (n_in < 15) return;
    const float* x      = (const float*)d_in[0];
    const float* Wi     = (const float*)d_in[1];
    const float* Wh     = (const float*)d_in[2];
    const float* Bg     = (const float*)d_in[3];
    const float* Wni    = (const float*)d_in[4];
    const float* Wnh    = (const float*)d_in[5];
    const float* Bni    = (const float*)d_in[6];
    const float* Bnh    = (const float*)d_in[7];
    const float* Winvi  = (const float*)d_in[8];
    const float* Winvh  = (const float*)d_in[9];
    const float* Binv   = (const float*)d_in[10];
    const float* Wninvi = (const float*)d_in[11];
    const float* Wninvh = (const float*)d_in[12];
    const float* Bninvi = (const float*)d_in[13];
    const float* Bninvh = (const float*)d_in[14];

    if (ws_size < WS_NEED) {
        hipMemsetAsync(d_out, 0, (size_t)out_size * 4, stream);
        return;
    }
    char* ws = (char*)d_ws;
    unsigned short* xb   = (unsigned short*)(ws + OFF_X);
    unsigned short* WinT = (unsigned short*)(ws + OFF_WINT);
    unsigned short* Wrec = (unsigned short*)(ws + OFF_WREC);
    float*          bias = (float*)(ws + OFF_BIAS);
    unsigned short* hbuf = (unsigned short*)(ws + OFF_H);
    unsigned int*   bar  = (unsigned int*)(ws + OFF_BAR);
    unsigned short* G    = (unsigned short*)(ws + OFF_G);

    hipMemsetAsync(ws + OFF_BAR, 0, SZ_BAR, stream);

    prep_kernel<<<4096, 256, 0, stream>>>(
        x, Wi, Wni, Winvi, Wninvi, Wh, Wnh, Winvh, Wninvh,
        Bg, Bni, Binv, Bninvi, xb, WinT, Wrec, bias);

    gemm_in<<<12288, 256, 0, stream>>>(xb, WinT, bias, G);

    hipFuncSetAttribute(reinterpret_cast<const void*>(&gru_rec),
                        hipFuncAttributeMaxDynamicSharedMemorySize, SMEM_TOT);
    gru_rec<<<256, 320, SMEM_TOT, stream>>>(
        G, Wrec, Bnh, Bninvh, hbuf, (float*)d_out, bar);
}